// Round 8
// baseline (9516.781 us; speedup 1.0000x reference)
//
#include <hip/hip_runtime.h>

// ScaledODENetFE: forward-Euler scan, T=44100, B=32, F=1, S=16, H=64.
// One wave per batch; lane k owns hidden unit k. VALU-issue-bound
// (~2.4 cyc/op marginal, R2->R3 evidence); DS hops are cheap (~20-40 cyc,
// R3->R6 evidence). R7 changes vs R6:
//  - r-combine: replace 16 readlane + 16 fma with LDS broadcast
//    (all lanes ds_write identical P to pbuf[lane&15]; 4x ds_read_b128)
//    + 8 v_pk_fma_f32 on the naturally-paired quads. S0 = pbuf[0] free.
//  - stage1 packed (v2f pk_mul/pk_fma).
//  - carry restructure (R4's, exonerated by R5's isolation): zbase =
//    fma(x_next, w1x, v) precomputed off-chain; z = zbase + R (1-add tail).
//  - b2[0] folded to store time: y0 += p0 per step; out = (y0 + n*b2[0])/sr.
//  - DPP bound_ctrl=1 (canonical fusible form for v_add_f32_dpp).
// permlane16/32_swap remains BANNED (R4/R5: wrong data on HW).

#define SRATE 44100.0f
#define T_TOTAL 44100
#define BATCH 32
#define HID 64
#define ST 16

typedef float v2f __attribute__((ext_vector_type(2)));

template <int CTRL>
__device__ __forceinline__ float dppmov(float x) {
    // bound_ctrl=1; all patterns used are full permutations (no invalid lanes)
    return __builtin_bit_cast(float,
        __builtin_amdgcn_update_dpp(0, __builtin_bit_cast(int, x),
                                    CTRL, 0xF, 0xF, true));
}

__device__ __forceinline__ float bcast(float v, int lane) {
    return __builtin_bit_cast(float,
        __builtin_amdgcn_readlane(__builtin_bit_cast(int, v), lane));
}

// tanh(z) = (t-1)/(t+1), t = 2^(2z*log2e). rcp ~1 ulp (validated R2-R6).
__device__ __forceinline__ float fast_tanh(float z) {
    z = __builtin_amdgcn_fmed3f(z, -30.f, 30.f);
    float t = __builtin_amdgcn_exp2f(z * 2.8853900817779268f);
    float r = __builtin_amdgcn_rcpf(t + 1.f);
    return (t - 1.f) * r;
}

__device__ __forceinline__ int parity(int v) { return __builtin_popcount(v) & 1; }

__global__ __launch_bounds__(64, 1)
void ScaledODENetFE_kernel(const float* __restrict__ x,
                           const float* __restrict__ W1,
                           const float* __restrict__ b1,
                           const float* __restrict__ W2,
                           const float* __restrict__ b2v,
                           float* __restrict__ out) {
    __shared__ __attribute__((aligned(16))) float pbuf[16];

    const int b = blockIdx.x;      // batch element
    const int lane = threadIdx.x;  // hidden unit k
    const int TM1 = T_TOTAL - 1;   // 44099 scan steps

    // ---- one-time precompute (lane k) ----
    float w1x = W1[lane];                       // W1[0][k]
    float w1yd[ST];
    #pragma unroll
    for (int s = 0; s < ST; ++s)
        w1yd[s] = W1[(1 + s) * HID + lane] / SRATE;

    float cseed = 0.f;                          // c_k = sum_s b2[s]*w1yd[s]
    #pragma unroll
    for (int s = 0; s < ST; ++s) cseed = fmaf(b2v[s], w1yd[s], cseed);
    const v2f cpair = (v2f){cseed, 0.f};

    v2f w1yd2[8];                               // pairs (2q, 2q+1)
    #pragma unroll
    for (int q = 0; q < 8; ++q) w1yd2[q] = (v2f){w1yd[2 * q], w1yd[2 * q + 1]};

    // Dual-basis lane phis for the permuted W2 layout (XOR gens 1,2,7,8).
    const int p1 = parity(lane & 5), p2 = parity(lane & 6);
    const int p3 = (lane >> 2) & 1, p4 = (lane >> 3) & 1;
    float wA[8], wB[8];
    #pragma unroll
    for (int j = 0; j < 8; ++j) {
        const int i = 2 * j;
        const int c1 = (i & 1) ^ p1;
        const int c2 = ((i >> 1) & 1) ^ p2;
        const int c3 = ((i >> 2) & 1) ^ p3;
        const int c4 = ((i >> 3) & 1) ^ p4;
        const int s = (c1 ? 1 : 0) ^ (c2 ? 2 : 0) ^ (c3 ? 7 : 0) ^ (c4 ? 8 : 0);
        wA[j] = W2[lane * ST + s];
        wB[j] = W2[(lane ^ 1) * ST + s];
    }
    v2f wA2[4], wB2[4];                         // stage-2 pairs (2m, 2m+1)
    #pragma unroll
    for (int m = 0; m < 4; ++m) {
        wA2[m] = (v2f){wA[2 * m], wA[2 * m + 1]};
        wB2[m] = (v2f){wB[2 * m], wB[2 * m + 1]};
    }

    const int bp32 = ((lane ^ 32) & 63) << 2;   // ds_bpermute byte addrs
    const int bp48 = ((lane ^ 48) & 63) << 2;
    const float b20 = b2v[0];

    float v  = b1[lane];                        // v carries b1 (y starts 0)
    float y0 = 0.f;                             // excludes the b2[0] terms

    if (lane == 0) out[b] = 0.f;                // row t=0 is zeros

    // Lane l holds x[(t0+l)*B + b]; prefetch one chunk ahead.
    float xv = x[min(lane, TM1 - 1) * BATCH + b];
    float z = fmaf(bcast(xv, 0), w1x, v);       // seed step 0

    for (int t0 = 0; t0 < TM1; t0 += 64) {
        float xvn = x[min(t0 + 64 + lane, TM1 - 1) * BATCH + b];
        const int nsteps = min(64, TM1 - t0);
        float outy = 0.f;

        #pragma unroll 4
        for (int kk = 0; kk < nsteps; ++kk) {
            float h = fast_tanh(z);

            // Off-chain prep for next step's z.
            const int nk = kk + 1;
            float xsrc = (nk == 64) ? xvn : xv;
            float xtn  = bcast(xsrc, nk & 63);
            float zbase = fmaf(xtn, w1x, v);    // uses v(t); z' = zbase + R

            // Stage 1 (xor1, fused, packed): u1 = hx*wB + h*wA.
            float hx = dppmov<0xB1>(h);         // quad_perm [1,0,3,2]
            v2f h2  = (v2f){h, h};
            v2f hx2 = (v2f){hx, hx};
            v2f u1p[4];
            #pragma unroll
            for (int m = 0; m < 4; ++m)
                u1p[m] = __builtin_elementwise_fma(hx2, wB2[m], h2 * wA2[m]);

            // Stage 2 (xor2 = quad_perm [2,3,0,1]).
            float u2[4];
            #pragma unroll
            for (int m = 0; m < 4; ++m)
                u2[m] = u1p[m].x + dppmov<0x4E>(u1p[m].y);

            // Stage 3 (xor7 = row_half_mirror).
            float u3a = u2[0] + dppmov<0x141>(u2[1]);
            float u3b = u2[2] + dppmov<0x141>(u2[3]);

            // Stage 4 (xor8 = row_ror:8).
            float P = u3a + dppmov<0x128>(u3b);

            // Cross-row combine: 3 independent DS ops (R6, proven bit-exact).
            int   Pi  = __builtin_bit_cast(int, P);
            float a16 = __builtin_bit_cast(float,
                        __builtin_amdgcn_ds_swizzle(Pi, 0x401F));       // P^16
            float a32 = __builtin_bit_cast(float,
                        __builtin_amdgcn_ds_bpermute(bp32, Pi));        // P^32
            float a48 = __builtin_bit_cast(float,
                        __builtin_amdgcn_ds_bpermute(bp48, Pi));        // P^48
            P = (P + a16) + (a32 + a48);
            // All 4 rows now hold identical p_{lane mod 16}.

            // Broadcast via LDS: identical-value 4-way write collisions are
            // deterministic; 2-way bank aliasing is free. DS pipe is in-order
            // per wave; __syncthreads lowers to a waitcnt for a 1-wave WG.
            pbuf[lane & 15] = P;
            __syncthreads();
            float4 pA = reinterpret_cast<const float4*>(pbuf)[0];  // p0..3
            float4 pB = reinterpret_cast<const float4*>(pbuf)[1];  // p4..7
            float4 pC = reinterpret_cast<const float4*>(pbuf)[2];  // p8..11
            float4 pD = reinterpret_cast<const float4*>(pbuf)[3];  // p12..15

            // y0 path: b2[0] folded to store time.
            y0 += pA.x;
            outy = (kk == lane) ? y0 : outy;

            // R = c + sum_s p_s*w1yd[s], packed: 4 chains of 2 pk_fma.
            v2f pr0 = (v2f){pA.x, pA.y}, pr1 = (v2f){pA.z, pA.w};
            v2f pr2 = (v2f){pB.x, pB.y}, pr3 = (v2f){pB.z, pB.w};
            v2f pr4 = (v2f){pC.x, pC.y}, pr5 = (v2f){pC.z, pC.w};
            v2f pr6 = (v2f){pD.x, pD.y}, pr7 = (v2f){pD.z, pD.w};
            v2f a0 = __builtin_elementwise_fma(pr0, w1yd2[0], cpair);
            a0 = __builtin_elementwise_fma(pr4, w1yd2[4], a0);
            v2f a1 = pr1 * w1yd2[1];
            a1 = __builtin_elementwise_fma(pr5, w1yd2[5], a1);
            v2f a2 = pr2 * w1yd2[2];
            a2 = __builtin_elementwise_fma(pr6, w1yd2[6], a2);
            v2f a3 = pr3 * w1yd2[3];
            a3 = __builtin_elementwise_fma(pr7, w1yd2[7], a3);
            v2f sv = (a0 + a1) + (a2 + a3);
            float R = sv.x + sv.y;

            z = zbase + R;       // critical-path tail: single add
            v = v + R;           // off-chain, needed next step
        }

        // Store: add back n*b2[0] (n = #steps accumulated), one IEEE div.
        if (lane < nsteps) {
            const int n = t0 + 1 + lane;
            out[n * BATCH + b] = fmaf((float)n, b20, outy) / SRATE;
        }
        xv = xvn;
    }
}

extern "C" void kernel_launch(void* const* d_in, const int* in_sizes, int n_in,
                              void* d_out, int out_size, void* d_ws, size_t ws_size,
                              hipStream_t stream) {
    const float* x  = (const float*)d_in[0];
    const float* W1 = (const float*)d_in[1];
    const float* b1 = (const float*)d_in[2];
    const float* W2 = (const float*)d_in[3];
    const float* b2 = (const float*)d_in[4];
    float* out = (float*)d_out;

    ScaledODENetFE_kernel<<<BATCH, 64, 0, stream>>>(x, W1, b1, W2, b2, out);
}

// Round 9
// 7529.983 us; speedup vs baseline: 1.2639x; 1.2639x over previous
//
#include <hip/hip_runtime.h>

// ScaledODENetFE: forward-Euler scan, T=44100, B=32, F=1, S=16, H=64.
// One wave per batch; lane k owns hidden unit k. Mixed chain+issue bound:
// chain ~240 cyc (tanh -> DPP tree -> 3 parallel DS -> readlane r-combine),
// issue ~160 cyc. Calibrated R7 lesson: on-chain DS hops cost ~40 cyc each
// (LDS broadcast round-trip regressed); readlane combine stays.
// R8 = R6 + off-chain/chain-only cuts, all individually validated:
//  - tanh: h = fma(-2, rcp(1 + exp2(2z*log2e)), 1)  == (t-1)/(t+1) exactly,
//    saturates to +-1 via inf/0 semantics -> no clamp. 5 ops, ~28 cyc.
//  - stage1 packed v_pk ops (numerics proven in R7's passing run).
//  - carry restructure (R7-proven): zbase = fma(x_next, w1x, v) off-chain;
//    critical tail is a single add z = zbase + R.
//  - b2[0] folded to store: y0 += p0; out = (y0 + n*b2[0])/sr (R7-proven).
// permlane16/32_swap BANNED (R4/R5: wrong data on HW).
// LDS broadcast of P BANNED on-chain (R7: +2 DS hops + barrier drain).

#define SRATE 44100.0f
#define T_TOTAL 44100
#define BATCH 32
#define HID 64
#define ST 16

typedef float v2f __attribute__((ext_vector_type(2)));

template <int CTRL>
__device__ __forceinline__ float dppmov(float x) {
    return __builtin_bit_cast(float,
        __builtin_amdgcn_update_dpp(0, __builtin_bit_cast(int, x),
                                    CTRL, 0xF, 0xF, false));
}

__device__ __forceinline__ float bcast(float v, int lane) {
    return __builtin_bit_cast(float,
        __builtin_amdgcn_readlane(__builtin_bit_cast(int, v), lane));
}

// tanh(z) = 1 - 2/(1+e^{2z}). z->+inf: exp2->inf, rcp->0, h->1.
// z->-inf: exp2->0, rcp(1)->1, h->-1. No clamp needed. ~1e-7 abs err.
__device__ __forceinline__ float fast_tanh(float z) {
    float t = __builtin_amdgcn_exp2f(z * 2.8853900817779268f); // 2*log2(e)
    float r = __builtin_amdgcn_rcpf(t + 1.f);
    return fmaf(-2.f, r, 1.f);
}

__device__ __forceinline__ int parity(int v) { return __builtin_popcount(v) & 1; }

__global__ __launch_bounds__(64, 1)
void ScaledODENetFE_kernel(const float* __restrict__ x,
                           const float* __restrict__ W1,
                           const float* __restrict__ b1,
                           const float* __restrict__ W2,
                           const float* __restrict__ b2v,
                           float* __restrict__ out) {
    const int b = blockIdx.x;      // batch element
    const int lane = threadIdx.x;  // hidden unit k
    const int TM1 = T_TOTAL - 1;   // 44099 scan steps

    // ---- one-time precompute (lane k) ----
    float w1x = W1[lane];                       // W1[0][k]
    float w1yd[ST];
    #pragma unroll
    for (int s = 0; s < ST; ++s)
        w1yd[s] = W1[(1 + s) * HID + lane] / SRATE;

    float c = 0.f;                              // c_k = sum_s b2[s]*w1yd[s]
    #pragma unroll
    for (int s = 0; s < ST; ++s) c = fmaf(b2v[s], w1yd[s], c);

    // Dual-basis lane phis for the permuted W2 layout (XOR gens 1,2,7,8).
    const int p1 = parity(lane & 5), p2 = parity(lane & 6);
    const int p3 = (lane >> 2) & 1, p4 = (lane >> 3) & 1;
    float wA[8], wB[8];
    #pragma unroll
    for (int j = 0; j < 8; ++j) {
        const int i = 2 * j;
        const int c1 = (i & 1) ^ p1;
        const int c2 = ((i >> 1) & 1) ^ p2;
        const int c3 = ((i >> 2) & 1) ^ p3;
        const int c4 = ((i >> 3) & 1) ^ p4;
        const int s = (c1 ? 1 : 0) ^ (c2 ? 2 : 0) ^ (c3 ? 7 : 0) ^ (c4 ? 8 : 0);
        wA[j] = W2[lane * ST + s];
        wB[j] = W2[(lane ^ 1) * ST + s];
    }
    v2f wA2[4], wB2[4];                         // stage-1 packed pairs
    #pragma unroll
    for (int m = 0; m < 4; ++m) {
        wA2[m] = (v2f){wA[2 * m], wA[2 * m + 1]};
        wB2[m] = (v2f){wB[2 * m], wB[2 * m + 1]};
    }

    const int bp32 = ((lane ^ 32) & 63) << 2;   // ds_bpermute byte addrs
    const int bp48 = ((lane ^ 48) & 63) << 2;
    const float b20 = b2v[0];

    float v  = b1[lane];                        // v carries b1 (y starts 0)
    float y0 = 0.f;                             // excludes b2[0] terms (folded)

    if (lane == 0) out[b] = 0.f;                // row t=0 is zeros

    // Lane l holds x[(t0+l)*B + b]; prefetch one chunk ahead.
    float xv = x[min(lane, TM1 - 1) * BATCH + b];
    float z = fmaf(bcast(xv, 0), w1x, v);       // seed step 0

    for (int t0 = 0; t0 < TM1; t0 += 64) {
        float xvn = x[min(t0 + 64 + lane, TM1 - 1) * BATCH + b];
        const int nsteps = min(64, TM1 - t0);
        float outy = 0.f;

        for (int kk = 0; kk < nsteps; ++kk) {
            float h = fast_tanh(z);

            // Off-chain prep for next step's z (issues during reduction).
            const int nk = kk + 1;
            float xsrc = (nk == 64) ? xvn : xv;
            float xtn  = bcast(xsrc, nk & 63);
            float zbase = fmaf(xtn, w1x, v);    // v_t; z' = zbase + R

            // Stage 1 (xor1, fused, packed): u1 = hx*wB + h*wA.
            float hx = dppmov<0xB1>(h);         // quad_perm [1,0,3,2]
            v2f h2  = (v2f){h, h};
            v2f hx2 = (v2f){hx, hx};
            v2f u1p[4];
            #pragma unroll
            for (int m = 0; m < 4; ++m)
                u1p[m] = __builtin_elementwise_fma(hx2, wB2[m], h2 * wA2[m]);

            // Stage 2 (xor2 = quad_perm [2,3,0,1]).
            float u2[4];
            #pragma unroll
            for (int m = 0; m < 4; ++m)
                u2[m] = u1p[m].x + dppmov<0x4E>(u1p[m].y);

            // Stage 3 (xor7 = row_half_mirror).
            float u3a = u2[0] + dppmov<0x141>(u2[1]);
            float u3b = u2[2] + dppmov<0x141>(u2[3]);

            // Stage 4 (xor8 = row_ror:8).
            float P = u3a + dppmov<0x128>(u3b);

            // Cross-row combine: 3 INDEPENDENT DS ops, one latency (R6).
            int   Pi  = __builtin_bit_cast(int, P);
            float a16 = __builtin_bit_cast(float,
                        __builtin_amdgcn_ds_swizzle(Pi, 0x401F));       // P^16
            float a32 = __builtin_bit_cast(float,
                        __builtin_amdgcn_ds_bpermute(bp32, Pi));        // P^32
            float a48 = __builtin_bit_cast(float,
                        __builtin_amdgcn_ds_bpermute(bp48, Pi));        // P^48
            P = (P + a16) + (a32 + a48);
            // Every lane now holds p_{lane mod 16}.

            // y0 path (b2[0] folded out; p0 CSEs with r-combine's bcast).
            y0 += bcast(P, 0);
            outy = (kk == lane) ? y0 : outy;

            // R = c + sum_s p_s*w1yd[s]: 4 chains, c seeded (R6 form —
            // readlane combine is chain-optimal per R7 lesson).
            float r0 = c, r1 = 0.f, r2 = 0.f, r3 = 0.f;
            #pragma unroll
            for (int q = 0; q < 4; ++q) {
                r0 = fmaf(bcast(P, q),      w1yd[q],      r0);
                r1 = fmaf(bcast(P, 4 + q),  w1yd[4 + q],  r1);
                r2 = fmaf(bcast(P, 8 + q),  w1yd[8 + q],  r2);
                r3 = fmaf(bcast(P, 12 + q), w1yd[12 + q], r3);
            }
            float R = (r0 + r1) + (r2 + r3);

            z = zbase + R;       // critical-path tail: single add
            v = v + R;           // off-chain, feeds next step's zbase
        }

        // Store: add back n*b2[0], one IEEE div, coalesced.
        if (lane < nsteps) {
            const int n = t0 + 1 + lane;
            out[n * BATCH + b] = fmaf((float)n, b20, outy) / SRATE;
        }
        xv = xvn;
    }
}

extern "C" void kernel_launch(void* const* d_in, const int* in_sizes, int n_in,
                              void* d_out, int out_size, void* d_ws, size_t ws_size,
                              hipStream_t stream) {
    const float* x  = (const float*)d_in[0];
    const float* W1 = (const float*)d_in[1];
    const float* b1 = (const float*)d_in[2];
    const float* W2 = (const float*)d_in[3];
    const float* b2 = (const float*)d_in[4];
    float* out = (float*)d_out;

    ScaledODENetFE_kernel<<<BATCH, 64, 0, stream>>>(x, W1, b1, W2, b2, out);
}